// Round 7
// baseline (545.998 us; speedup 1.0000x reference)
//
#include <hip/hip_runtime.h>
#include <math.h>

#define MM 512
#define KK 100000
#define NBLK 512              // 2 blocks/CU, guaranteed co-resident via launch_bounds(512,4)
#define WPB  8                // 512 threads = 8 waves
#define NWV  (NBLK * WPB)     // 4096 streaming waves

// ws float offsets:
#define OFF_V      0          // v = W^T a1                [512]
#define OFF_U      512        // u = W^T a2                [512]
#define OFF_BAR    1024       // 4 barrier counters (int)  [4]
#define OFF_ZTOT   1040       // total Z                   [1]
#define OFF_PMAX   1536       // per-block max of s        [512]
#define OFF_SUMU   2048       // per-block sum x.u         [512]
#define OFF_ZPART  2560      // per-block Z partials       [512]
#define OFF_PART2  3072       // stage-2 colsum partials   [16*512]
#define OFF_S      16384      // s_i = x_i . v             [100000]
#define OFF_PART   131072     // per-block colsums         [512*512]

__device__ inline float waveSum(float v){
  #pragma unroll
  for(int off = 32; off > 0; off >>= 1) v += __shfl_down(v, off, 64);
  return v;   // total in lane 0
}
__device__ inline float waveMax(float v){
  #pragma unroll
  for(int off = 32; off > 0; off >>= 1) v = fmaxf(v, __shfl_down(v, off, 64));
  return v;
}
__device__ inline float dot8(float4 x0, float4 x1, float4 v0, float4 v1){
  return x0.x*v0.x + x0.y*v0.y + x0.z*v0.z + x0.w*v0.w
       + x1.x*v1.x + x1.y*v1.y + x1.z*v1.z + x1.w*v1.w;
}

// Cross-XCD grid barrier (proved correct in R6 at 256 blocks): dedicated
// counter per use; release add + agent-scope spin + fences.
__device__ inline void gbar(int* bar, int nblk){
  __syncthreads();
  if(threadIdx.x == 0){
    __threadfence();
    __hip_atomic_fetch_add(bar, 1, __ATOMIC_RELEASE, __HIP_MEMORY_SCOPE_AGENT);
    while(__hip_atomic_load(bar, __ATOMIC_RELAXED, __HIP_MEMORY_SCOPE_AGENT) < nblk)
      __builtin_amdgcn_s_sleep(2);
    __threadfence();
  }
  __syncthreads();
}

__global__ __launch_bounds__(512, 4)   // 4 waves/EU min -> 2 blocks/CU, VGPR<=128
void k_all(const float* __restrict__ x,
           const float* __restrict__ W,
           const float* __restrict__ b,
           const float* __restrict__ a,
           float* __restrict__ ws,
           float* __restrict__ out){
  __shared__ float lw[WPB * 512];   // 16 KB: P0 partials / P2 transpose
  __shared__ float red[16];

  float* v     = ws + OFF_V;
  float* u     = ws + OFF_U;
  int*   bar   = (int*)(ws + OFF_BAR);
  float* Ztot  = ws + OFF_ZTOT;
  float* pmax  = ws + OFF_PMAX;
  float* sumUp = ws + OFF_SUMU;
  float* zpart = ws + OFF_ZPART;
  float* part2 = ws + OFF_PART2;
  float* s     = ws + OFF_S;
  float* part  = ws + OFF_PART;

  int tid  = threadIdx.x;
  int lane = tid & 63;
  int wid  = tid >> 6;
  int bid  = blockIdx.x;
  int gw   = bid * WPB + wid;

  // ---------- P0 (blocks 0..7): v,u = W^T a1, W^T a2 — non-atomic ----------
  if(bid < 8){
    int jl = tid & 63, kg = tid >> 6;      // wave kg covers k in [kg*64, kg*64+64)
    int j  = bid * 64 + jl;
    float pv = 0.f, pu = 0.f;
    for(int k = kg * 64; k < kg * 64 + 64; k++){
      float w = W[(size_t)k * MM + j];
      pv += w * a[k];
      pu += w * a[MM + k];
    }
    lw[kg * 64 + jl]       = pv;
    lw[512 + kg * 64 + jl] = pu;
    __syncthreads();
    if(tid < 64){
      float sv = 0.f, su = 0.f;
      #pragma unroll
      for(int g = 0; g < 8; g++){ sv += lw[g*64 + tid]; su += lw[512 + g*64 + tid]; }
      v[bid * 64 + tid] = sv;
      u[bid * 64 + tid] = su;
    }
  }
  gbar(&bar[0], NBLK);

  // ---------- P1: s_i = x_i.v (8-row staged batch), per-block sumU & max ----------
  {
    const float4* v4 = (const float4*)v;
    const float4* u4 = (const float4*)u;
    float4 v0 = v4[lane], v1 = v4[64 + lane];
    float4 u0 = u4[lane], u1 = u4[64 + lane];
    float accU = 0.f;
    float wmax = -3.4e38f;

    int myN = (KK - 1 - gw) / NWV + 1;   // 24 or 25 rows
    int k = 0;
    for(; k + 8 <= myN; k += 8){
      // stage: 16 independent float4 loads in flight before any use
      float4 xa[8], xb[8];
      #pragma unroll
      for(int r = 0; r < 8; r++){
        const float4* xr = (const float4*)(x + ((size_t)gw + (size_t)(k + r) * NWV) * MM);
        xa[r] = xr[lane];
        xb[r] = xr[64 + lane];
      }
      float d[8];
      #pragma unroll
      for(int r = 0; r < 8; r++){
        d[r]  = dot8(xa[r], xb[r], v0, v1);
        accU += dot8(xa[r], xb[r], u0, u1);
      }
      #pragma unroll
      for(int off = 1; off < 64; off <<= 1){
        #pragma unroll
        for(int r = 0; r < 8; r++) d[r] += __shfl_xor(d[r], off, 64);
      }
      float m01 = fmaxf(fmaxf(d[0], d[1]), fmaxf(d[2], d[3]));
      float m23 = fmaxf(fmaxf(d[4], d[5]), fmaxf(d[6], d[7]));
      wmax = fmaxf(wmax, fmaxf(m01, m23));
      float s0 = (lane & 1) ? d[1] : d[0];
      float s1 = (lane & 1) ? d[3] : d[2];
      float s2 = (lane & 1) ? d[5] : d[4];
      float s3 = (lane & 1) ? d[7] : d[6];
      float t0 = (lane & 2) ? s1 : s0;
      float t1 = (lane & 2) ? s3 : s2;
      float rr = (lane & 4) ? t1 : t0;
      if(lane < 8) s[(size_t)gw + (size_t)(k + lane) * NWV] = rr;
    }
    for(; k < myN; k++){
      size_t row = (size_t)gw + (size_t)k * NWV;
      const float4* xr = (const float4*)(x + row * MM);
      float4 x0 = xr[lane];
      float4 x1 = xr[64 + lane];
      float d = dot8(x0, x1, v0, v1);
      accU += dot8(x0, x1, u0, u1);
      #pragma unroll
      for(int off = 1; off < 64; off <<= 1) d += __shfl_xor(d, off, 64);
      wmax = fmaxf(wmax, d);
      if(lane == 0) s[row] = d;
    }

    float ws_ = waveSum(accU);
    if(lane == 0){ red[wid] = ws_; red[8 + wid] = wmax; }
    __syncthreads();
    if(tid == 0){
      float su = 0.f, mx = -3.4e38f;
      #pragma unroll
      for(int i = 0; i < 8; i++){ su += red[i]; mx = fmaxf(mx, red[8 + i]); }
      sumUp[bid] = su;
      pmax[bid]  = mx;
    }
  }
  gbar(&bar[1], NBLK);

  // ---------- P2: weights + per-block colsum partials ----------
  {
    // prologue: c = b.(a1+a2) + sumU/K ; m = max(0, max_i s_i + c)
    float cv = b[tid] * (a[tid] + a[MM + tid]) + sumUp[tid] * (1.0f / (float)KK);
    float mx = pmax[tid];
    float csum = waveSum(cv);
    mx = waveMax(mx);
    if(lane == 0){ red[wid] = csum; red[8 + wid] = mx; }
    __syncthreads();
    float c = 0.f, m = -3.4e38f;
    #pragma unroll
    for(int i = 0; i < 8; i++){ c += red[i]; m = fmaxf(m, red[8 + i]); }
    m = fmaxf(0.f, m + c);

    // main streaming loop (8-row staged batch)
    float4 a0 = make_float4(0,0,0,0), a1 = make_float4(0,0,0,0);
    float accZ = 0.f;
    int myN = (KK - 1 - gw) / NWV + 1;
    int k = 0;
    for(; k + 8 <= myN; k += 8){
      float w[8];
      #pragma unroll
      for(int r = 0; r < 8; r++)
        w[r] = s[(size_t)gw + (size_t)(k + r) * NWV];
      float4 xa[8], xb[8];
      #pragma unroll
      for(int r = 0; r < 8; r++){
        const float4* xr = (const float4*)(x + ((size_t)gw + (size_t)(k + r) * NWV) * MM);
        xa[r] = xr[lane];
        xb[r] = xr[64 + lane];
      }
      #pragma unroll
      for(int r = 0; r < 8; r++){
        w[r] = __expf(fmaxf(w[r] + c, 0.f) - m);
        accZ += w[r];
      }
      #pragma unroll
      for(int r = 0; r < 8; r++){
        a0.x += w[r] * xa[r].x; a0.y += w[r] * xa[r].y;
        a0.z += w[r] * xa[r].z; a0.w += w[r] * xa[r].w;
        a1.x += w[r] * xb[r].x; a1.y += w[r] * xb[r].y;
        a1.z += w[r] * xb[r].z; a1.w += w[r] * xb[r].w;
      }
    }
    for(; k < myN; k++){
      size_t row = (size_t)gw + (size_t)k * NWV;
      float w = __expf(fmaxf(s[row] + c, 0.f) - m);
      accZ += w;
      const float4* xr = (const float4*)(x + row * MM);
      float4 x0 = xr[lane];
      float4 x1 = xr[64 + lane];
      a0.x += w * x0.x; a0.y += w * x0.y; a0.z += w * x0.z; a0.w += w * x0.w;
      a1.x += w * x1.x; a1.y += w * x1.y; a1.z += w * x1.z; a1.w += w * x1.w;
    }

    // tail: cross-wave sum via LDS, coalesced non-atomic partial output
    float zw = waveSum(accZ);
    __syncthreads();                 // all prologue reads of red complete
    float4* lw4 = (float4*)lw;
    lw4[wid * 128 + lane * 2]     = a0;   // lane l: cols 4l+q     at w*512+l*8+q
    lw4[wid * 128 + lane * 2 + 1] = a1;   // cols 256+4l+q at w*512+l*8+4+q
    if(lane == 0) red[wid] = zw;
    __syncthreads();
    int addr = (tid < 256) ? ((tid >> 2) * 8 + (tid & 3))
                           : (((tid - 256) >> 2) * 8 + 4 + ((tid - 256) & 3));
    float cs = 0.f;
    #pragma unroll
    for(int w8 = 0; w8 < WPB; w8++) cs += lw[w8 * 512 + addr];
    part[(size_t)bid * 512 + tid] = cs;
    if(tid == 0){
      float z = 0.f;
      #pragma unroll
      for(int i = 0; i < 8; i++) z += red[i];
      zpart[bid] = z * (1.0f / 64.0f);
    }
  }
  gbar(&bar[2], NBLK);

  // ---------- P3a: fold part[512][512] -> part2[16][512]; block 16: Ztot ----------
  if(bid < 16){
    const float* p = part + (size_t)bid * 32 * 512;
    float cs = 0.f;
    #pragma unroll 4
    for(int r = 0; r < 32; r++) cs += p[r * 512 + tid];
    part2[bid * 512 + tid] = cs;
  } else if(bid == 16){
    float zz = zpart[tid];
    float zw = waveSum(zz);
    if(lane == 0) red[wid] = zw;
    __syncthreads();
    if(tid == 0){
      float z = 0.f;
      #pragma unroll
      for(int i = 0; i < 8; i++) z += red[i];
      Ztot[0] = z;
    }
  }
  gbar(&bar[3], NBLK);

  // ---------- P3b: block 0 finalizes ----------
  if(bid == 0){
    float A = 0.f;
    #pragma unroll
    for(int r = 0; r < 16; r++) A += part2[r * 512 + tid];
    out[tid] = A / Ztot[0];
  }
}

extern "C" void kernel_launch(void* const* d_in, const int* in_sizes, int n_in,
                              void* d_out, int out_size, void* d_ws, size_t ws_size,
                              hipStream_t stream) {
  const float* x = (const float*)d_in[0];
  const float* W = (const float*)d_in[1];
  const float* b = (const float*)d_in[2];
  const float* a = (const float*)d_in[3];
  float* ws  = (float*)d_ws;
  float* out = (float*)d_out;

  // zero only the 4 barrier counters (ws is re-poisoned 0xAA before every call)
  hipMemsetAsync(ws + OFF_BAR, 0, 4 * sizeof(int), stream);

  k_all<<<NBLK, 512, 0, stream>>>(x, W, b, a, ws, out);
}

// Round 8
// 356.534 us; speedup vs baseline: 1.5314x; 1.5314x over previous
//
#include <hip/hip_runtime.h>
#include <math.h>

#define MM 512
#define KK 100000
#define NBP 2048              // pass1/pass2 blocks
#define TPB 256               // 4 waves
#define NWP (NBP * 4)         // 8192 waves
#define RPW 13                // ceil(KK / NWP) rows per wave, contiguous
#define NOUT 32               // k_out blocks

// ws float layout:
// [0..512)      v = W^T a1
// [512..1024)   u = W^T a2
// [1024..1536)  acc  (k_out accumulator)            -- zeroed
// [1536]        Z                                    -- zeroed
// [1537]        cnt (int)                            -- zeroed
// [1540..1542)  cm = {c, m}
// [2048..4096)  pmax  per-block max of s   [2048]
// [4096..6144)  sumU  per-block sum x.u    [2048]
// [6144..8192)  zpart per-block Z partial  [2048]
// [16384..+KK)  s
// [131072..)    part[2048][512] colsum partials (4 MB)

__device__ inline float waveSum(float v){
  #pragma unroll
  for(int off = 32; off > 0; off >>= 1) v += __shfl_down(v, off, 64);
  return v;   // total in lane 0
}
__device__ inline float waveMax(float v){
  #pragma unroll
  for(int off = 32; off > 0; off >>= 1) v = fmaxf(v, __shfl_down(v, off, 64));
  return v;
}
__device__ inline float dot8(float4 x0, float4 x1, float4 v0, float4 v1){
  return x0.x*v0.x + x0.y*v0.y + x0.z*v0.z + x0.w*v0.w
       + x1.x*v1.x + x1.y*v1.y + x1.z*v1.z + x1.w*v1.w;
}

// v,u = W^T a1, W^T a2 — non-atomic (proven in R6 P0). 8 blocks x 512.
__global__ __launch_bounds__(512) void k_vu(const float* __restrict__ W,
                                            const float* __restrict__ a,
                                            float* __restrict__ v,
                                            float* __restrict__ u){
  __shared__ float lw[1024];
  int jl = threadIdx.x & 63, kg = threadIdx.x >> 6;
  int j  = blockIdx.x * 64 + jl;
  float pv = 0.f, pu = 0.f;
  for(int k = kg * 64; k < kg * 64 + 64; k++){
    float w = W[(size_t)k * MM + j];
    pv += w * a[k];
    pu += w * a[MM + k];
  }
  lw[kg * 64 + jl]       = pv;
  lw[512 + kg * 64 + jl] = pu;
  __syncthreads();
  if(threadIdx.x < 64){
    float sv = 0.f, su = 0.f;
    #pragma unroll
    for(int g = 0; g < 8; g++){
      sv += lw[g * 64 + threadIdx.x];
      su += lw[512 + g * 64 + threadIdx.x];
    }
    v[blockIdx.x * 64 + threadIdx.x] = sv;
    u[blockIdx.x * 64 + threadIdx.x] = su;
  }
}

// Pass 1: wave gw owns contiguous rows [gw*RPW, gw*RPW+RPW).
// Minimal-VGPR 1-row loop; 32 waves/CU provide the latency hiding.
__global__ __launch_bounds__(256, 8) void k_pass1(const float* __restrict__ x,
                                                  const float* __restrict__ vv,
                                                  const float* __restrict__ uu,
                                                  float* __restrict__ s,
                                                  float* __restrict__ sumUp,
                                                  float* __restrict__ pmax){
  __shared__ float red[8];
  int tid  = threadIdx.x;
  int lane = tid & 63;
  int wid  = tid >> 6;
  int gw   = blockIdx.x * 4 + wid;

  const float4* v4 = (const float4*)vv;
  const float4* u4 = (const float4*)uu;
  float4 v0 = v4[lane], v1 = v4[64 + lane];
  float4 u0 = u4[lane], u1 = u4[64 + lane];
  float accU = 0.f;
  float wmax = -3.4e38f;

  int row0 = gw * RPW;
  int rowE = min(row0 + RPW, KK);
  for(int row = row0; row < rowE; row++){
    const float4* xr = (const float4*)(x + (size_t)row * MM);
    float4 x0 = xr[lane];
    float4 x1 = xr[64 + lane];
    float d = dot8(x0, x1, v0, v1);
    accU   += dot8(x0, x1, u0, u1);
    #pragma unroll
    for(int off = 1; off < 64; off <<= 1) d += __shfl_xor(d, off, 64);
    wmax = fmaxf(wmax, d);
    if(lane == 0) s[row] = d;
  }

  float ws_ = waveSum(accU);
  if(lane == 0){ red[wid] = ws_; red[4 + wid] = wmax; }
  __syncthreads();
  if(tid == 0){
    sumUp[blockIdx.x] = red[0] + red[1] + red[2] + red[3];
    pmax[blockIdx.x]  = fmaxf(fmaxf(red[4], red[5]), fmaxf(red[6], red[7]));
  }
}

// Single block: c = b.(a1+a2) + (sum x.u)/K ; m = max(0, max_i s_i + c)
__global__ __launch_bounds__(512) void k_mid(const float* __restrict__ b,
                                             const float* __restrict__ a,
                                             const float* __restrict__ sumUp,
                                             const float* __restrict__ pmax,
                                             float* __restrict__ cm){
  __shared__ float ls[8];
  __shared__ float lm[8];
  int tid = threadIdx.x;
  float t = b[tid] * (a[tid] + a[MM + tid]);
  float mx = -3.4e38f;
  #pragma unroll
  for(int i = 0; i < 4; i++){
    t  += sumUp[tid + i * 512] * (1.0f / (float)KK);
    mx  = fmaxf(mx, pmax[tid + i * 512]);
  }
  float wsum = waveSum(t);
  mx = waveMax(mx);
  if((tid & 63) == 0){ ls[tid >> 6] = wsum; lm[tid >> 6] = mx; }
  __syncthreads();
  if(tid == 0){
    float c = 0.f, m = -3.4e38f;
    #pragma unroll
    for(int i = 0; i < 8; i++){ c += ls[i]; m = fmaxf(m, lm[i]); }
    cm[0] = c;
    cm[1] = fmaxf(0.f, m + c);
  }
}

// Pass 2: w_i = exp(relu(s_i+c)-m); per-block colsums -> part (non-atomic),
// per-block Z -> zpart (non-atomic).
__global__ __launch_bounds__(256, 8) void k_pass2(const float* __restrict__ x,
                                                  const float* __restrict__ s,
                                                  const float* __restrict__ cm,
                                                  float* __restrict__ part,
                                                  float* __restrict__ zpart){
  __shared__ float lw[1024];   // 4 waves x 256 (two halves sequentially)
  __shared__ float red[4];
  int tid  = threadIdx.x;
  int lane = tid & 63;
  int wid  = tid >> 6;
  int gw   = blockIdx.x * 4 + wid;
  float c = cm[0], m = cm[1];

  float4 a0 = make_float4(0,0,0,0), a1 = make_float4(0,0,0,0);
  float accZ = 0.f;
  int row0 = gw * RPW;
  int rowE = min(row0 + RPW, KK);
  for(int row = row0; row < rowE; row++){
    float w = __expf(fmaxf(s[row] + c, 0.f) - m);
    accZ += w;
    const float4* xr = (const float4*)(x + (size_t)row * MM);
    float4 x0 = xr[lane];
    float4 x1 = xr[64 + lane];
    a0.x += w * x0.x; a0.y += w * x0.y; a0.z += w * x0.z; a0.w += w * x0.w;
    a1.x += w * x1.x; a1.y += w * x1.y; a1.z += w * x1.z; a1.w += w * x1.w;
  }

  // tail: cross-wave sum via LDS (two rounds to keep LDS at 4 KB)
  float zw = waveSum(accZ);
  if(lane == 0) red[wid] = zw;

  float4* lw4 = (float4*)lw;
  lw4[wid * 64 + lane] = a0;              // lane l: cols 4l..4l+3 at w*256+l*4
  __syncthreads();
  float cs0 = lw[tid] + lw[256 + tid] + lw[512 + tid] + lw[768 + tid];
  __syncthreads();
  lw4[wid * 64 + lane] = a1;              // cols 256+4l..
  __syncthreads();
  float cs1 = lw[tid] + lw[256 + tid] + lw[512 + tid] + lw[768 + tid];

  part[(size_t)blockIdx.x * 512 + tid]       = cs0;
  part[(size_t)blockIdx.x * 512 + 256 + tid] = cs1;
  if(tid == 0)
    zpart[blockIdx.x] = (red[0] + red[1] + red[2] + red[3]) * (1.0f / 64.0f);
}

// Reduce part[2048][512] and zpart[2048]; last block writes out = acc/Z.
__global__ __launch_bounds__(256) void k_out(const float* __restrict__ part,
                                             const float* __restrict__ zpart,
                                             float* __restrict__ acc,
                                             float* __restrict__ Zws,
                                             int* __restrict__ cnt,
                                             float* __restrict__ out){
  __shared__ int lastf;
  int tid = threadIdx.x;
  const float* p = part + (size_t)blockIdx.x * (NBP / NOUT) * 512;
  float s0 = 0.f, s1 = 0.f, zz = 0.f;
  #pragma unroll 8
  for(int r = 0; r < NBP / NOUT; r++){
    s0 += p[r * 512 + tid];
    s1 += p[r * 512 + 256 + tid];
  }
  if(tid < NBP / NOUT) zz = zpart[blockIdx.x * (NBP / NOUT) + tid];
  zz = waveSum(zz);
  atomicAdd(&acc[tid],       s0);
  atomicAdd(&acc[tid + 256], s1);
  if(tid == 0) atomicAdd(Zws, zz);
  __threadfence();
  if(tid == 0) lastf = (atomicAdd(cnt, 1) == NOUT - 1) ? 1 : 0;
  __syncthreads();
  if(lastf){
    float z  = atomicAdd(Zws, 0.0f);                // coherent reads
    float v0 = atomicAdd(&acc[tid],       0.0f);
    float v1 = atomicAdd(&acc[tid + 256], 0.0f);
    out[tid]       = v0 / z;
    out[tid + 256] = v1 / z;
  }
}

extern "C" void kernel_launch(void* const* d_in, const int* in_sizes, int n_in,
                              void* d_out, int out_size, void* d_ws, size_t ws_size,
                              hipStream_t stream) {
  const float* x = (const float*)d_in[0];
  const float* W = (const float*)d_in[1];
  const float* b = (const float*)d_in[2];
  const float* a = (const float*)d_in[3];
  float* ws  = (float*)d_ws;
  float* out = (float*)d_out;

  float* v     = ws;
  float* u     = ws + 512;
  float* acc   = ws + 1024;
  float* Zws   = ws + 1536;
  int*   cnt   = (int*)(ws + 1537);
  float* cm    = ws + 1540;
  float* pmax  = ws + 2048;
  float* sumUp = ws + 4096;
  float* zpart = ws + 6144;
  float* s     = ws + 16384;
  float* part  = ws + 131072;

  // zero only acc, Z, cnt (floats [1024,1544))
  hipMemsetAsync(ws + 1024, 0, 520 * sizeof(float), stream);

  k_vu   <<<8,    512, 0, stream>>>(W, a, v, u);
  k_pass1<<<NBP,  TPB, 0, stream>>>(x, v, u, s, sumUp, pmax);
  k_mid  <<<1,    512, 0, stream>>>(b, a, sumUp, pmax, cm);
  k_pass2<<<NBP,  TPB, 0, stream>>>(x, s, cm, part, zpart);
  k_out  <<<NOUT, 256, 0, stream>>>(part, zpart, acc, Zws, cnt, out);
}